// Round 23
// baseline (276.423 us; speedup 1.0000x reference)
//
#include <hip/hip_runtime.h>

typedef unsigned short u16;
typedef short s8v __attribute__((ext_vector_type(8)));
typedef float f4v __attribute__((ext_vector_type(4)));

#define D_LQ 4096
#define D_N 4
#define D_E 1024
#define D_M 16384
#define D_COLS 4096

__device__ __forceinline__ u16 f2b(float f) {
  unsigned u = __float_as_uint(f);
  return (u16)((u + 0x7FFFu + ((u >> 16) & 1u)) >> 16);
}
__device__ __forceinline__ float b2f(u16 x) {
  return __uint_as_float(((unsigned)x) << 16);
}
__device__ __forceinline__ s8v cvt8(float4 a, float4 b) {
  s8v o;
  o[0] = (short)f2b(a.x); o[1] = (short)f2b(a.y);
  o[2] = (short)f2b(a.z); o[3] = (short)f2b(a.w);
  o[4] = (short)f2b(b.x); o[5] = (short)f2b(b.y);
  o[6] = (short)f2b(b.z); o[7] = (short)f2b(b.w);
  return o;
}
__device__ __forceinline__ void gl_lds16(const void* g, void* l) {
  __builtin_amdgcn_global_load_lds(
      (const __attribute__((address_space(1))) void*)g,
      (__attribute__((address_space(3))) void*)l, 16, 0, 0);
}
__device__ __forceinline__ void barr() {
  asm volatile("" ::: "memory");
  __builtin_amdgcn_s_barrier();
  asm volatile("" ::: "memory");
}
#define WAITV3 asm volatile("s_waitcnt vmcnt(3)" ::: "memory")
#define WAITV0 asm volatile("s_waitcnt vmcnt(0)" ::: "memory")

// ---- f32 -> bf16 conversion, grid-stride (G11: ~2048 blocks, MLP per thread) ----
__global__ void cvt_gs(const float* __restrict__ in, u16* __restrict__ out, long n8) {
  long step = (long)gridDim.x * 256;
  for (long i = (long)blockIdx.x * 256 + threadIdx.x; i < n8; i += step) {
    const float4* p = (const float4*)in + 2 * i;
    float4 a = p[0], b = p[1];
    *(s8v*)(out + i * 8) = cvt8(a, b);
  }
}

// k and v in one launch, grid-stride; grid (1024, 2)
__global__ void cvt_kv_gs(const float* __restrict__ K, const float* __restrict__ V,
                          u16* __restrict__ OK, u16* __restrict__ OV, long n8) {
  const float* in = blockIdx.y ? V : K;
  u16* out = blockIdx.y ? OV : OK;
  long step = (long)gridDim.x * 256;
  for (long i = (long)blockIdx.x * 256 + threadIdx.x; i < n8; i += step) {
    const float4* p = (const float4*)in + 2 * i;
    float4 a = p[0], b = p[1];
    *(s8v*)(out + i * 8) = cvt8(a, b);
  }
}

// all 4 weights in one launch; grid (nW8/256, 4)
__global__ void cvt_w4(const float* __restrict__ W0, const float* __restrict__ W1,
                       const float* __restrict__ W2, const float* __restrict__ W3,
                       u16* __restrict__ O0, u16* __restrict__ O1,
                       u16* __restrict__ O2, u16* __restrict__ O3) {
  long i = (long)blockIdx.x * 256 + threadIdx.x;
  int w = blockIdx.y;
  const float* W = (w == 0) ? W0 : (w == 1) ? W1 : (w == 2) ? W2 : W3;
  u16* O = (w == 0) ? O0 : (w == 1) ? O1 : (w == 2) ? O2 : O3;
  const float4* p = (const float4*)W + 2 * i;
  float4 a = p[0], b = p[1];
  *(s8v*)(O + i * 8) = cvt8(a, b);
}

// ---- 256x128 tile, BK=32, 512-thr (8 waves 4Mx2N), triple-buffered counted-vmcnt ----
// LDS row-pair layout (conflict-free, R15-verified): logical (row, granule khi) at
// phys line p=row>>1, slot G' = (khi + 4*(row&1)) ^ (p&7).
// Single barrier per K-tile (R18-verified). Keep `#pragma unroll 1` (R19: unroll-3
// collapses occupancy 39%->20%, +17 us).
__device__ __forceinline__ void stageA(const u16* __restrict__ src0, long rstride,
                                       u16* __restrict__ lds, int tid) {
#pragma unroll
  for (int L = 0; L < 2; L++) {
    int g = tid + L * 512;          // 1024 granules (256 rows x 4)
    int p = g >> 3, Gp = g & 7;
    int G = Gp ^ (p & 7);
    int row = 2 * p + (G >> 2);
    int gcol = G & 3;
    gl_lds16(src0 + (long)row * rstride + gcol * 8, lds + g * 8);
  }
}
__device__ __forceinline__ void stageB(const u16* __restrict__ src0, long rstride,
                                       u16* __restrict__ lds, int tid) {
  int g = tid;                      // 512 granules (128 rows x 4)
  int p = g >> 3, Gp = g & 7;
  int G = Gp ^ (p & 7);
  int row = 2 * p + (G >> 2);
  int gcol = G & 3;
  gl_lds16(src0 + (long)row * rstride + gcol * 8, lds + g * 8);
}
__device__ __forceinline__ s8v fr(const u16* __restrict__ lds, int row, int khi) {
  int p = row >> 1;
  int G = khi + ((row & 1) << 2);
  int Gp = G ^ (p & 7);
  return *(const s8v*)(lds + p * 64 + Gp * 8);
}

// EPI: 0 = bf16 + bias; 1 = fused q-softmax (bf16); 2 = f32 + bias strided rows.
template <int EPI, bool STRIDED>
__global__ __launch_bounds__(512, 2)
void gemmK(const u16* __restrict__ A, const u16* __restrict__ B,
           const float* __restrict__ bias, void* __restrict__ Cv) {
  __shared__ u16 As[3][256 * 32];
  __shared__ u16 Bs[3][128 * 32];
  const int tid = threadIdx.x;
  const int lane = tid & 63, r15 = lane & 15, khi = lane >> 4;
  const int w = tid >> 6, wm = w >> 1, wn = w & 1;   // 4M x 2N
  int gg = STRIDED ? (int)((blockIdx.z * gridDim.y + blockIdx.y) * gridDim.x + blockIdx.x)
                   : (int)(blockIdx.y * gridDim.x + blockIdx.x);
  int s = (gg & 7) * 64 + (gg >> 3);       // bijective XCD swizzle over 512 wgs
  int zn, by, bx;
  if (STRIDED) { zn = s >> 7; by = (s >> 3) & 15; bx = s & 7; }
  else         { zn = 0;      by = s >> 3;        bx = s & 7; }
  const long arst = STRIDED ? 4096 : 1024;
  const u16* abase = STRIDED ? (A + ((long)(by * 256) * 4 + zn) * 1024)
                             : (A + (long)(by * 256) * 1024);
  const u16* bbase = B + ((STRIDED ? (long)zn * 1024 : 0) + bx * 128) * 1024;

  // prologue: tiles 0,1 in flight (3 loads/thread each); gate tile0
  stageA(abase + 0, arst, As[0], tid);
  stageB(bbase + 0, 1024, Bs[0], tid);
  stageA(abase + 32, arst, As[1], tid);
  stageB(bbase + 32, 1024, Bs[1], tid);
  WAITV3;
  barr();

  f4v acc[4][4] = {};
#pragma unroll 1
  for (int t = 0; t < 32; t++) {
    const u16* as = As[t % 3];
    const u16* bs = Bs[t % 3];
    s8v bfr[4], afr[4];
#pragma unroll
    for (int nf = 0; nf < 4; nf++) bfr[nf] = fr(bs, wn * 64 + nf * 16 + r15, khi);
#pragma unroll
    for (int i = 0; i < 4; i++) afr[i] = fr(as, wm * 64 + i * 16 + r15, khi);
    if (t < 30) {
      stageA(abase + (t + 2) * 32, arst, As[(t + 2) % 3], tid);
      stageB(bbase + (t + 2) * 32, 1024, Bs[(t + 2) % 3], tid);
    }
    __builtin_amdgcn_s_setprio(1);
#pragma unroll
    for (int i = 0; i < 4; i++)
#pragma unroll
      for (int nf = 0; nf < 4; nf++)
        acc[i][nf] = __builtin_amdgcn_mfma_f32_16x16x32_bf16(afr[i], bfr[nf], acc[i][nf], 0, 0, 0);
    __builtin_amdgcn_s_setprio(0);
    if (t < 30) { WAITV3; } else { WAITV0; }
    barr();
  }

  const int colb = bx * 128 + wn * 64;
  const long rowb = (long)by * 256 + wm * 64;
  if (EPI == 1) {
    float bb[4];
#pragma unroll
    for (int nf = 0; nf < 4; nf++) bb[nf] = bias[colb + nf * 16 + r15];
    u16* C = (u16*)Cv;
#pragma unroll
    for (int m = 0; m < 4; m++) {
#pragma unroll
      for (int j = 0; j < 4; j++) {
        float e[4], ssum = 0.f;
#pragma unroll
        for (int nf = 0; nf < 4; nf++) { e[nf] = __expf(acc[m][nf][j] + bb[nf]); ssum += e[nf]; }
        ssum += __shfl_xor(ssum, 1);
        ssum += __shfl_xor(ssum, 2);
        ssum += __shfl_xor(ssum, 4);
        ssum += __shfl_xor(ssum, 8);
        float rs = 1.f / ssum;
        long row = rowb + m * 16 + khi * 4 + j;
#pragma unroll
        for (int nf = 0; nf < 4; nf++)
          C[row * 1024 + colb + nf * 16 + r15] = f2b(e[nf] * rs);
      }
    }
  } else if (EPI == 0) {
    u16* C = (u16*)Cv;
#pragma unroll
    for (int m = 0; m < 4; m++)
#pragma unroll
      for (int nf = 0; nf < 4; nf++) {
        int col = colb + nf * 16 + r15;
        float bb = bias[col];
#pragma unroll
        for (int j = 0; j < 4; j++) {
          long row = rowb + m * 16 + khi * 4 + j;
          C[row * 1024 + col] = f2b(acc[m][nf][j] + bb);
        }
      }
  } else {
    float* C = (float*)Cv;
#pragma unroll
    for (int m = 0; m < 4; m++)
#pragma unroll
      for (int nf = 0; nf < 4; nf++) {
        int col = colb + nf * 16 + r15;
        float bb = bias[col];
#pragma unroll
        for (int j = 0; j < 4; j++) {
          long row = rowb + m * 16 + khi * 4 + j;      // l index
          C[(row * 4 + zn) * 1024 + col] = acc[m][nf][j] + bb;
        }
      }
  }
}

// ---- v' partial per (head g, lchunk of 512), UNNORMALIZED exp(k) weights; also
// accumulates softmax denominators. Vectorized s8v loads, hoisted above barrier. ----
__global__ __launch_bounds__(256)
void vprime_part(const u16* __restrict__ kw, const u16* __restrict__ vp,
                 float* __restrict__ part, float* __restrict__ kpart) {
  __shared__ float Ks[64 * 64];
  __shared__ float Vs[64 * 64];
  int g = blockIdx.x, lc = blockIdx.y;
  int n = g >> 4, h = g & 15;
  int tid = threadIdx.x;
  int dt = (tid >> 4) * 4, et = (tid & 15) * 4;
  int r = tid >> 2, c16 = (tid & 3) * 16;
  float acc[4][4] = {};
  float ksum[4] = {0.f, 0.f, 0.f, 0.f};
  long base = (long)lc * 512 * D_COLS + n * D_E + h * 64;
  for (int ch = 0; ch < 8; ch++) {
    long off = base + (long)(ch * 64 + r) * D_COLS + c16;
    s8v k0 = *(const s8v*)(kw + off);
    s8v k1 = *(const s8v*)(kw + off + 8);
    s8v v0 = *(const s8v*)(vp + off);
    s8v v1 = *(const s8v*)(vp + off + 8);
    __syncthreads();
#pragma unroll
    for (int qq = 0; qq < 8; qq++) {
      Ks[r * 64 + c16 + qq]     = __expf(b2f((u16)k0[qq]));
      Ks[r * 64 + c16 + 8 + qq] = __expf(b2f((u16)k1[qq]));
      Vs[r * 64 + c16 + qq]     = b2f((u16)v0[qq]);
      Vs[r * 64 + c16 + 8 + qq] = b2f((u16)v1[qq]);
    }
    __syncthreads();
    for (int l = 0; l < 64; l++) {
      float kf[4], vf[4];
#pragma unroll
      for (int i = 0; i < 4; i++) { kf[i] = Ks[l * 64 + dt + i]; vf[i] = Vs[l * 64 + et + i]; }
#pragma unroll
      for (int i = 0; i < 4; i++) {
        ksum[i] += kf[i];
#pragma unroll
        for (int j = 0; j < 4; j++) acc[i][j] += kf[i] * vf[j];
      }
    }
  }
#pragma unroll
  for (int i = 0; i < 4; i++)
#pragma unroll
    for (int j = 0; j < 4; j++)
      part[(((long)lc * 64 + g) * 64 + (dt + i)) * 64 + et + j] = acc[i][j];
  if (et == 0) {
#pragma unroll
    for (int i = 0; i < 4; i++)
      kpart[((long)lc * 64 + g) * 64 + dt + i] = ksum[i];
  }
}

// reduce partials, normalize by summed denominators -> v' bf16 [g][d][e]
__global__ void vprime_red(const float* __restrict__ part, const float* __restrict__ kpart,
                           u16* __restrict__ vpb) {
  long id = (long)blockIdx.x * 256 + threadIdx.x;   // g*4096 + d*64 + e
  long g = id >> 12, d = (id >> 6) & 63;
  float s = 0.f, ks = 0.f;
  for (int lc = 0; lc < 8; lc++) {
    s += part[(long)lc * 64 * 4096 + id];
    ks += kpart[((long)lc * 64 + g) * 64 + d];
  }
  vpb[id] = f2b(s / ks);
}

// ---- U[n][o][h*64+d] = sum_e Wo[o][h*64+e] * v'[g][d][e]  (per head g=(n,h)) ----
__global__ __launch_bounds__(256)
void u_mfma(const u16* __restrict__ Wob, const u16* __restrict__ vpb,
            u16* __restrict__ Ub) {
  __shared__ u16 Qs[128 * 64];
  __shared__ u16 Ps[64 * 64];
  const int ot = blockIdx.x, g = blockIdx.y;
  const int nb = g >> 4, h = g & 15;
  const int tid = threadIdx.x;
  const int lane = tid & 63, r15 = lane & 15, khi = lane >> 4;
  const int w = tid >> 6;
#pragma unroll
  for (int it = 0; it < 4; it++) {
    int c = it * 256 + tid;
    int row = c >> 3, cb = (c & 7) * 16;
    int swz = cb ^ ((row & 7) << 4);
    gl_lds16(Wob + (long)(ot * 128 + row) * D_E + h * 64 + (swz >> 1), Qs + c * 8);
  }
#pragma unroll
  for (int it = 0; it < 2; it++) {
    int c = it * 256 + tid;
    int row = c >> 3, cb = (c & 7) * 16;
    int swz = cb ^ ((row & 7) << 4);
    gl_lds16(vpb + ((long)g << 12) + row * 64 + (swz >> 1), Ps + c * 8);
  }
  __syncthreads();
  f4v acc[2][4] = {};
#pragma unroll
  for (int ks = 0; ks < 2; ks++) {
    s8v af[2], bf[4];
#pragma unroll
    for (int mf = 0; mf < 2; mf++) {
      int row = w * 32 + mf * 16 + r15;
      int boff = row * 128 + ((ks * 64 + khi * 16) ^ ((row & 7) << 4));
      af[mf] = *(const s8v*)((const char*)Qs + boff);
    }
#pragma unroll
    for (int nf = 0; nf < 4; nf++) {
      int row = nf * 16 + r15;
      int boff = row * 128 + ((ks * 64 + khi * 16) ^ ((row & 7) << 4));
      bf[nf] = *(const s8v*)((const char*)Ps + boff);
    }
#pragma unroll
    for (int mf = 0; mf < 2; mf++)
#pragma unroll
      for (int nf = 0; nf < 4; nf++)
        acc[mf][nf] = __builtin_amdgcn_mfma_f32_16x16x32_bf16(af[mf], bf[nf], acc[mf][nf], 0, 0, 0);
  }
#pragma unroll
  for (int mf = 0; mf < 2; mf++) {
#pragma unroll
    for (int nf = 0; nf < 4; nf++) {
#pragma unroll
      for (int j = 0; j < 4; j++) {
        int o = ot * 128 + w * 32 + mf * 16 + khi * 4 + j;
        int d = nf * 16 + r15;
        Ub[((long)nb * 1024 + o) * 1024 + h * 64 + d] = f2b(acc[mf][nf][j]);
      }
    }
  }
}

__global__ void sentinel(float* __restrict__ out, int wsbad) {
  if (blockIdx.x == 0 && threadIdx.x == 0 && wsbad) {
    out[0] += 100.0f;
  }
}

extern "C" void kernel_launch(void* const* d_in, const int* in_sizes, int n_in,
                              void* d_out, int out_size, void* d_ws, size_t ws_size,
                              hipStream_t stream) {
  const float* q  = (const float*)d_in[0];
  const float* k  = (const float*)d_in[1];
  const float* v  = (const float*)d_in[2];
  const float* Wq = (const float*)d_in[3];
  const float* bq = (const float*)d_in[4];
  const float* Wk = (const float*)d_in[5];
  const float* bk = (const float*)d_in[6];
  const float* Wv = (const float*)d_in[7];
  const float* bv = (const float*)d_in[8];
  const float* Wo = (const float*)d_in[9];
  const float* bo = (const float*)d_in[10];

  char* ws = (char*)d_ws;
  size_t off = 0;
  u16* kb; u16* vb; float* part; float* kpart; u16* vpb;
  u16* xbk; u16* xbv; u16* Wqb; u16* Wkb; u16* Wvb; u16* Wob; u16* Ub;
  kb    = (u16*)(ws + off);   off += (size_t)D_M * D_E * 2;       // 32 MB
  vb    = (u16*)(ws + off);   off += (size_t)D_M * D_E * 2;       // 32 MB
  part  = (float*)(ws + off); off += (size_t)8 * 64 * 4096 * 4;   // 8 MB
  kpart = (float*)(ws + off); off += (size_t)8 * 64 * 64 * 4;     // 128 KB
  vpb   = (u16*)(ws + off);   off += (size_t)64 * 4096 * 2;
  xbk   = (u16*)(ws + off);   off += (size_t)D_M * D_E * 2;       // 32 MB
  xbv   = (u16*)(ws + off);   off += (size_t)D_M * D_E * 2;       // 32 MB
  Wqb   = (u16*)(ws + off);   off += (size_t)D_E * D_E * 2;
  Wkb   = (u16*)(ws + off);   off += (size_t)D_E * D_E * 2;
  Wvb   = (u16*)(ws + off);   off += (size_t)D_E * D_E * 2;
  Wob   = (u16*)(ws + off);   off += (size_t)D_E * D_E * 2;
  Ub    = (u16*)(ws + off);   off += (size_t)4 * 1024 * 1024 * 2; // 8 MB
  size_t need = off;
  u16* qsm = kb;   // reuse: kb free after vprime_part consumed k-weights
  int wsbad = (ws_size < need) ? 1 : 0;

  const long nX8 = (long)D_M * D_E / 8;
  const long nW8 = (long)D_E * D_E / 8;
  dim3 blk(256);
  dim3 blk5(512);

  // weights -> bf16 (one launch)
  cvt_w4<<<dim3(nW8 / 256, 4), blk, 0, stream>>>(Wq, Wk, Wv, Wo, Wqb, Wkb, Wvb, Wob);

  // k+v inputs -> bf16 (grid-stride, ~2048 blocks total)
  cvt_kv_gs<<<dim3(1024, 2), blk, 0, stream>>>(k, v, xbk, xbv, nX8);

  // k, v projections (256x128 engine, bf16 out)
  gemmK<0, false><<<dim3(8, 64), blk5, 0, stream>>>(xbk, Wkb, bk, (void*)kb);
  gemmK<0, false><<<dim3(8, 64), blk5, 0, stream>>>(xbv, Wvb, bv, (void*)vb);

  // v' = exp(k)^T v per head, denominators fused
  vprime_part<<<dim3(64, 8), blk, 0, stream>>>(kb, vb, part, kpart);
  vprime_red<<<dim3(64 * 4096 / 256), blk, 0, stream>>>(part, kpart, vpb);

  // U = v' @ Wo-slice^T per (n,h)
  u_mfma<<<dim3(8, 64), blk, 0, stream>>>(Wob, vpb, Ub);

  // q projection with fused softmax -> qsm (kb reuse; xbk free after k-gemm)
  cvt_gs<<<dim3(2048), blk, 0, stream>>>(q, xbk, nX8);
  gemmK<1, false><<<dim3(8, 64), blk5, 0, stream>>>(xbk, Wqb, bq, (void*)qsm);

  // out = qsm @ U^T + bo (per batch n, strided)
  gemmK<2, true><<<dim3(8, 16, 4), blk5, 0, stream>>>(qsm, Ub, bo, d_out);

  sentinel<<<dim3(1), dim3(64), 0, stream>>>((float*)d_out, wsbad);
}

// Round 24
// 272.936 us; speedup vs baseline: 1.0128x; 1.0128x over previous
//
#include <hip/hip_runtime.h>

typedef unsigned short u16;
typedef short s8v __attribute__((ext_vector_type(8)));
typedef float f4v __attribute__((ext_vector_type(4)));

#define D_LQ 4096
#define D_N 4
#define D_E 1024
#define D_M 16384
#define D_COLS 4096

__device__ __forceinline__ u16 f2b(float f) {
  unsigned u = __float_as_uint(f);
  return (u16)((u + 0x7FFFu + ((u >> 16) & 1u)) >> 16);
}
__device__ __forceinline__ float b2f(u16 x) {
  return __uint_as_float(((unsigned)x) << 16);
}
__device__ __forceinline__ s8v cvt8(float4 a, float4 b) {
  s8v o;
  o[0] = (short)f2b(a.x); o[1] = (short)f2b(a.y);
  o[2] = (short)f2b(a.z); o[3] = (short)f2b(a.w);
  o[4] = (short)f2b(b.x); o[5] = (short)f2b(b.y);
  o[6] = (short)f2b(b.z); o[7] = (short)f2b(b.w);
  return o;
}
__device__ __forceinline__ void gl_lds16(const void* g, void* l) {
  __builtin_amdgcn_global_load_lds(
      (const __attribute__((address_space(1))) void*)g,
      (__attribute__((address_space(3))) void*)l, 16, 0, 0);
}
__device__ __forceinline__ void barr() {
  asm volatile("" ::: "memory");
  __builtin_amdgcn_s_barrier();
  asm volatile("" ::: "memory");
}
#define WAITV3 asm volatile("s_waitcnt vmcnt(3)" ::: "memory")
#define WAITV0 asm volatile("s_waitcnt vmcnt(0)" ::: "memory")

// ---- f32 -> bf16 conversion, 8 elems/thread ----
__global__ void cvt_bf16(const float* __restrict__ in, u16* __restrict__ out, long n8) {
  long i = (long)blockIdx.x * 256 + threadIdx.x;
  if (i >= n8) return;
  const float4* p = (const float4*)in + 2 * i;
  float4 a = p[0], b = p[1];
  *(s8v*)(out + i * 8) = cvt8(a, b);
}

// k and v in one launch; grid (n8/256, 2)
__global__ void cvt_kv(const float* __restrict__ K, const float* __restrict__ V,
                       u16* __restrict__ OK, u16* __restrict__ OV, long n8) {
  long i = (long)blockIdx.x * 256 + threadIdx.x;
  if (i >= n8) return;
  const float* in = blockIdx.y ? V : K;
  u16* out = blockIdx.y ? OV : OK;
  const float4* p = (const float4*)in + 2 * i;
  float4 a = p[0], b = p[1];
  *(s8v*)(out + i * 8) = cvt8(a, b);
}

// all 4 weights in one launch; grid (nW8/256, 4)
__global__ void cvt_w4(const float* __restrict__ W0, const float* __restrict__ W1,
                       const float* __restrict__ W2, const float* __restrict__ W3,
                       u16* __restrict__ O0, u16* __restrict__ O1,
                       u16* __restrict__ O2, u16* __restrict__ O3) {
  long i = (long)blockIdx.x * 256 + threadIdx.x;
  int w = blockIdx.y;
  const float* W = (w == 0) ? W0 : (w == 1) ? W1 : (w == 2) ? W2 : W3;
  u16* O = (w == 0) ? O0 : (w == 1) ? O1 : (w == 2) ? O2 : O3;
  const float4* p = (const float4*)W + 2 * i;
  float4 a = p[0], b = p[1];
  *(s8v*)(O + i * 8) = cvt8(a, b);
}

// ---- 256x128 tile, BK=32, 512-thr (8 waves 4Mx2N), triple-buffered counted-vmcnt ----
// LDS row-pair layout (conflict-free, R15-verified): logical (row, granule khi) at
// phys line p=row>>1, slot G' = (khi + 4*(row&1)) ^ (p&7).
// Single barrier per K-tile (R18-verified). Keep `#pragma unroll 1` (R19: unroll-3
// collapses occupancy 39%->20%, +17 us).
__device__ __forceinline__ void stageA(const u16* __restrict__ src0, long rstride,
                                       u16* __restrict__ lds, int tid) {
#pragma unroll
  for (int L = 0; L < 2; L++) {
    int g = tid + L * 512;          // 1024 granules (256 rows x 4)
    int p = g >> 3, Gp = g & 7;
    int G = Gp ^ (p & 7);
    int row = 2 * p + (G >> 2);
    int gcol = G & 3;
    gl_lds16(src0 + (long)row * rstride + gcol * 8, lds + g * 8);
  }
}
__device__ __forceinline__ void stageB(const u16* __restrict__ src0, long rstride,
                                       u16* __restrict__ lds, int tid) {
  int g = tid;                      // 512 granules (128 rows x 4)
  int p = g >> 3, Gp = g & 7;
  int G = Gp ^ (p & 7);
  int row = 2 * p + (G >> 2);
  int gcol = G & 3;
  gl_lds16(src0 + (long)row * rstride + gcol * 8, lds + g * 8);
}
__device__ __forceinline__ s8v fr(const u16* __restrict__ lds, int row, int khi) {
  int p = row >> 1;
  int G = khi + ((row & 1) << 2);
  int Gp = G ^ (p & 7);
  return *(const s8v*)(lds + p * 64 + Gp * 8);
}

// EPI: 0 = bf16 + bias; 1 = fused q-softmax (bf16); 2 = f32 + bias strided rows.
template <int EPI, bool STRIDED>
__global__ __launch_bounds__(512, 2)
void gemmK(const u16* __restrict__ A, const u16* __restrict__ B,
           const float* __restrict__ bias, void* __restrict__ Cv) {
  __shared__ u16 As[3][256 * 32];
  __shared__ u16 Bs[3][128 * 32];
  const int tid = threadIdx.x;
  const int lane = tid & 63, r15 = lane & 15, khi = lane >> 4;
  const int w = tid >> 6, wm = w >> 1, wn = w & 1;   // 4M x 2N
  int gg = STRIDED ? (int)((blockIdx.z * gridDim.y + blockIdx.y) * gridDim.x + blockIdx.x)
                   : (int)(blockIdx.y * gridDim.x + blockIdx.x);
  int s = (gg & 7) * 64 + (gg >> 3);       // bijective XCD swizzle over 512 wgs
  int zn, by, bx;
  if (STRIDED) { zn = s >> 7; by = (s >> 3) & 15; bx = s & 7; }
  else         { zn = 0;      by = s >> 3;        bx = s & 7; }
  const long arst = STRIDED ? 4096 : 1024;
  const u16* abase = STRIDED ? (A + ((long)(by * 256) * 4 + zn) * 1024)
                             : (A + (long)(by * 256) * 1024);
  const u16* bbase = B + ((STRIDED ? (long)zn * 1024 : 0) + bx * 128) * 1024;

  // prologue: tiles 0,1 in flight (3 loads/thread each); gate tile0
  stageA(abase + 0, arst, As[0], tid);
  stageB(bbase + 0, 1024, Bs[0], tid);
  stageA(abase + 32, arst, As[1], tid);
  stageB(bbase + 32, 1024, Bs[1], tid);
  WAITV3;
  barr();

  f4v acc[4][4] = {};
#pragma unroll 1
  for (int t = 0; t < 32; t++) {
    const u16* as = As[t % 3];
    const u16* bs = Bs[t % 3];
    s8v bfr[4], afr[4];
#pragma unroll
    for (int nf = 0; nf < 4; nf++) bfr[nf] = fr(bs, wn * 64 + nf * 16 + r15, khi);
#pragma unroll
    for (int i = 0; i < 4; i++) afr[i] = fr(as, wm * 64 + i * 16 + r15, khi);
    if (t < 30) {
      stageA(abase + (t + 2) * 32, arst, As[(t + 2) % 3], tid);
      stageB(bbase + (t + 2) * 32, 1024, Bs[(t + 2) % 3], tid);
    }
    __builtin_amdgcn_s_setprio(1);
#pragma unroll
    for (int i = 0; i < 4; i++)
#pragma unroll
      for (int nf = 0; nf < 4; nf++)
        acc[i][nf] = __builtin_amdgcn_mfma_f32_16x16x32_bf16(afr[i], bfr[nf], acc[i][nf], 0, 0, 0);
    __builtin_amdgcn_s_setprio(0);
    if (t < 30) { WAITV3; } else { WAITV0; }
    barr();
  }

  const int colb = bx * 128 + wn * 64;
  const long rowb = (long)by * 256 + wm * 64;
  if (EPI == 1) {
    float bb[4];
#pragma unroll
    for (int nf = 0; nf < 4; nf++) bb[nf] = bias[colb + nf * 16 + r15];
    u16* C = (u16*)Cv;
#pragma unroll
    for (int m = 0; m < 4; m++) {
#pragma unroll
      for (int j = 0; j < 4; j++) {
        float e[4], ssum = 0.f;
#pragma unroll
        for (int nf = 0; nf < 4; nf++) { e[nf] = __expf(acc[m][nf][j] + bb[nf]); ssum += e[nf]; }
        ssum += __shfl_xor(ssum, 1);
        ssum += __shfl_xor(ssum, 2);
        ssum += __shfl_xor(ssum, 4);
        ssum += __shfl_xor(ssum, 8);
        float rs = 1.f / ssum;
        long row = rowb + m * 16 + khi * 4 + j;
#pragma unroll
        for (int nf = 0; nf < 4; nf++)
          C[row * 1024 + colb + nf * 16 + r15] = f2b(e[nf] * rs);
      }
    }
  } else if (EPI == 0) {
    u16* C = (u16*)Cv;
#pragma unroll
    for (int m = 0; m < 4; m++)
#pragma unroll
      for (int nf = 0; nf < 4; nf++) {
        int col = colb + nf * 16 + r15;
        float bb = bias[col];
#pragma unroll
        for (int j = 0; j < 4; j++) {
          long row = rowb + m * 16 + khi * 4 + j;
          C[row * 1024 + col] = f2b(acc[m][nf][j] + bb);
        }
      }
  } else {
    float* C = (float*)Cv;
#pragma unroll
    for (int m = 0; m < 4; m++)
#pragma unroll
      for (int nf = 0; nf < 4; nf++) {
        int col = colb + nf * 16 + r15;
        float bb = bias[col];
#pragma unroll
        for (int j = 0; j < 4; j++) {
          long row = rowb + m * 16 + khi * 4 + j;      // l index
          C[(row * 4 + zn) * 1024 + col] = acc[m][nf][j] + bb;
        }
      }
  }
}

// ---- v' partial per (head g, lchunk of 512), UNNORMALIZED exp(k) weights; also
// accumulates softmax denominators. Vectorized s8v loads, hoisted above barrier. ----
__global__ __launch_bounds__(256)
void vprime_part(const u16* __restrict__ kw, const u16* __restrict__ vp,
                 float* __restrict__ part, float* __restrict__ kpart) {
  __shared__ float Ks[64 * 64];
  __shared__ float Vs[64 * 64];
  int g = blockIdx.x, lc = blockIdx.y;
  int n = g >> 4, h = g & 15;
  int tid = threadIdx.x;
  int dt = (tid >> 4) * 4, et = (tid & 15) * 4;
  int r = tid >> 2, c16 = (tid & 3) * 16;
  float acc[4][4] = {};
  float ksum[4] = {0.f, 0.f, 0.f, 0.f};
  long base = (long)lc * 512 * D_COLS + n * D_E + h * 64;
  for (int ch = 0; ch < 8; ch++) {
    long off = base + (long)(ch * 64 + r) * D_COLS + c16;
    s8v k0 = *(const s8v*)(kw + off);
    s8v k1 = *(const s8v*)(kw + off + 8);
    s8v v0 = *(const s8v*)(vp + off);
    s8v v1 = *(const s8v*)(vp + off + 8);
    __syncthreads();
#pragma unroll
    for (int qq = 0; qq < 8; qq++) {
      Ks[r * 64 + c16 + qq]     = __expf(b2f((u16)k0[qq]));
      Ks[r * 64 + c16 + 8 + qq] = __expf(b2f((u16)k1[qq]));
      Vs[r * 64 + c16 + qq]     = b2f((u16)v0[qq]);
      Vs[r * 64 + c16 + 8 + qq] = b2f((u16)v1[qq]);
    }
    __syncthreads();
    for (int l = 0; l < 64; l++) {
      float kf[4], vf[4];
#pragma unroll
      for (int i = 0; i < 4; i++) { kf[i] = Ks[l * 64 + dt + i]; vf[i] = Vs[l * 64 + et + i]; }
#pragma unroll
      for (int i = 0; i < 4; i++) {
        ksum[i] += kf[i];
#pragma unroll
        for (int j = 0; j < 4; j++) acc[i][j] += kf[i] * vf[j];
      }
    }
  }
#pragma unroll
  for (int i = 0; i < 4; i++)
#pragma unroll
    for (int j = 0; j < 4; j++)
      part[(((long)lc * 64 + g) * 64 + (dt + i)) * 64 + et + j] = acc[i][j];
  if (et == 0) {
#pragma unroll
    for (int i = 0; i < 4; i++)
      kpart[((long)lc * 64 + g) * 64 + dt + i] = ksum[i];
  }
}

// reduce partials, normalize by summed denominators -> v' bf16 [g][d][e]
__global__ void vprime_red(const float* __restrict__ part, const float* __restrict__ kpart,
                           u16* __restrict__ vpb) {
  long id = (long)blockIdx.x * 256 + threadIdx.x;   // g*4096 + d*64 + e
  long g = id >> 12, d = (id >> 6) & 63;
  float s = 0.f, ks = 0.f;
  for (int lc = 0; lc < 8; lc++) {
    s += part[(long)lc * 64 * 4096 + id];
    ks += kpart[((long)lc * 64 + g) * 64 + d];
  }
  vpb[id] = f2b(s / ks);
}

// ---- U[n][o][h*64+d] = sum_e Wo[o][h*64+e] * v'[g][d][e]  (per head g=(n,h)) ----
__global__ __launch_bounds__(256)
void u_mfma(const u16* __restrict__ Wob, const u16* __restrict__ vpb,
            u16* __restrict__ Ub) {
  __shared__ u16 Qs[128 * 64];
  __shared__ u16 Ps[64 * 64];
  const int ot = blockIdx.x, g = blockIdx.y;
  const int nb = g >> 4, h = g & 15;
  const int tid = threadIdx.x;
  const int lane = tid & 63, r15 = lane & 15, khi = lane >> 4;
  const int w = tid >> 6;
#pragma unroll
  for (int it = 0; it < 4; it++) {
    int c = it * 256 + tid;
    int row = c >> 3, cb = (c & 7) * 16;
    int swz = cb ^ ((row & 7) << 4);
    gl_lds16(Wob + (long)(ot * 128 + row) * D_E + h * 64 + (swz >> 1), Qs + c * 8);
  }
#pragma unroll
  for (int it = 0; it < 2; it++) {
    int c = it * 256 + tid;
    int row = c >> 3, cb = (c & 7) * 16;
    int swz = cb ^ ((row & 7) << 4);
    gl_lds16(vpb + ((long)g << 12) + row * 64 + (swz >> 1), Ps + c * 8);
  }
  __syncthreads();
  f4v acc[2][4] = {};
#pragma unroll
  for (int ks = 0; ks < 2; ks++) {
    s8v af[2], bf[4];
#pragma unroll
    for (int mf = 0; mf < 2; mf++) {
      int row = w * 32 + mf * 16 + r15;
      int boff = row * 128 + ((ks * 64 + khi * 16) ^ ((row & 7) << 4));
      af[mf] = *(const s8v*)((const char*)Qs + boff);
    }
#pragma unroll
    for (int nf = 0; nf < 4; nf++) {
      int row = nf * 16 + r15;
      int boff = row * 128 + ((ks * 64 + khi * 16) ^ ((row & 7) << 4));
      bf[nf] = *(const s8v*)((const char*)Ps + boff);
    }
#pragma unroll
    for (int mf = 0; mf < 2; mf++)
#pragma unroll
      for (int nf = 0; nf < 4; nf++)
        acc[mf][nf] = __builtin_amdgcn_mfma_f32_16x16x32_bf16(af[mf], bf[nf], acc[mf][nf], 0, 0, 0);
  }
#pragma unroll
  for (int mf = 0; mf < 2; mf++) {
#pragma unroll
    for (int nf = 0; nf < 4; nf++) {
#pragma unroll
      for (int j = 0; j < 4; j++) {
        int o = ot * 128 + w * 32 + mf * 16 + khi * 4 + j;
        int d = nf * 16 + r15;
        Ub[((long)nb * 1024 + o) * 1024 + h * 64 + d] = f2b(acc[mf][nf][j]);
      }
    }
  }
}

__global__ void sentinel(float* __restrict__ out, int wsbad) {
  if (blockIdx.x == 0 && threadIdx.x == 0 && wsbad) {
    out[0] += 100.0f;
  }
}

extern "C" void kernel_launch(void* const* d_in, const int* in_sizes, int n_in,
                              void* d_out, int out_size, void* d_ws, size_t ws_size,
                              hipStream_t stream) {
  const float* q  = (const float*)d_in[0];
  const float* k  = (const float*)d_in[1];
  const float* v  = (const float*)d_in[2];
  const float* Wq = (const float*)d_in[3];
  const float* bq = (const float*)d_in[4];
  const float* Wk = (const float*)d_in[5];
  const float* bk = (const float*)d_in[6];
  const float* Wv = (const float*)d_in[7];
  const float* bv = (const float*)d_in[8];
  const float* Wo = (const float*)d_in[9];
  const float* bo = (const float*)d_in[10];

  char* ws = (char*)d_ws;
  size_t off = 0;
  u16* kb; u16* vb; float* part; float* kpart; u16* vpb;
  u16* xbk; u16* xbv; u16* Wqb; u16* Wkb; u16* Wvb; u16* Wob; u16* Ub;
  kb    = (u16*)(ws + off);   off += (size_t)D_M * D_E * 2;       // 32 MB
  vb    = (u16*)(ws + off);   off += (size_t)D_M * D_E * 2;       // 32 MB
  part  = (float*)(ws + off); off += (size_t)8 * 64 * 4096 * 4;   // 8 MB
  kpart = (float*)(ws + off); off += (size_t)8 * 64 * 64 * 4;     // 128 KB
  vpb   = (u16*)(ws + off);   off += (size_t)64 * 4096 * 2;
  xbk   = (u16*)(ws + off);   off += (size_t)D_M * D_E * 2;       // 32 MB
  xbv   = (u16*)(ws + off);   off += (size_t)D_M * D_E * 2;       // 32 MB
  Wqb   = (u16*)(ws + off);   off += (size_t)D_E * D_E * 2;
  Wkb   = (u16*)(ws + off);   off += (size_t)D_E * D_E * 2;
  Wvb   = (u16*)(ws + off);   off += (size_t)D_E * D_E * 2;
  Wob   = (u16*)(ws + off);   off += (size_t)D_E * D_E * 2;
  Ub    = (u16*)(ws + off);   off += (size_t)4 * 1024 * 1024 * 2; // 8 MB
  size_t need = off;
  u16* qsm = kb;   // reuse: kb free after vprime_part consumed k-weights
  int wsbad = (ws_size < need) ? 1 : 0;

  const long nX8 = (long)D_M * D_E / 8;
  const long nW8 = (long)D_E * D_E / 8;
  dim3 blk(256);
  dim3 blk5(512);

  // weights -> bf16 (one launch)
  cvt_w4<<<dim3(nW8 / 256, 4), blk, 0, stream>>>(Wq, Wk, Wv, Wo, Wqb, Wkb, Wvb, Wob);

  // k+v inputs -> bf16 (one launch, separate buffers)
  cvt_kv<<<dim3(nX8 / 256, 2), blk, 0, stream>>>(k, v, xbk, xbv, nX8);

  // k, v projections (256x128 engine, bf16 out)
  gemmK<0, false><<<dim3(8, 64), blk5, 0, stream>>>(xbk, Wkb, bk, (void*)kb);
  gemmK<0, false><<<dim3(8, 64), blk5, 0, stream>>>(xbv, Wvb, bv, (void*)vb);

  // v' = exp(k)^T v per head, denominators fused
  vprime_part<<<dim3(64, 8), blk, 0, stream>>>(kb, vb, part, kpart);
  vprime_red<<<dim3(64 * 4096 / 256), blk, 0, stream>>>(part, kpart, vpb);

  // U = v' @ Wo-slice^T per (n,h)
  u_mfma<<<dim3(8, 64), blk, 0, stream>>>(Wob, vpb, Ub);

  // q projection with fused softmax -> qsm (kb reuse; xbk free after k-gemm)
  cvt_bf16<<<dim3(nX8 / 256), blk, 0, stream>>>(q, xbk, nX8);
  gemmK<1, false><<<dim3(8, 64), blk5, 0, stream>>>(xbk, Wqb, bq, (void*)qsm);

  // out = qsm @ U^T + bo (per batch n, strided)
  gemmK<2, true><<<dim3(8, 16, 4), blk5, 0, stream>>>(qsm, Ub, bo, d_out);

  sentinel<<<dim3(1), dim3(64), 0, stream>>>((float*)d_out, wsbad);
}